// Round 1
// baseline (45602.438 us; speedup 1.0000x reference)
//
#include <hip/hip_runtime.h>
#include <hip/hip_bf16.h>

#define S_LEN 8192
#define CLEN 16
#define WDIM 256
#define CDIM 64
#define CHID 128
#define WHID 512
#define GDIM 2048   // 4*WHID
#define NTAG 64
#define KDIM 384    // WDIM + CHID
#define NWG 32      // workgroups in sequential kernel

__device__ __forceinline__ float sigmoidf_(float x) {
  return 1.0f / (1.0f + __expf(-x));
}
__device__ __forceinline__ float tanhf_(float x) {
  // safe tanh: 1 - 2/(e^{2x}+1); correct limits at +-inf without NaN
  return 1.0f - 2.0f / (__expf(2.0f * x) + 1.0f);
}

// ---------------------------------------------------------------------------
// K1: batched char LSTM. 16 words per block (two groups of 8), 256 threads.
// thread j (0..127) owns hidden unit j for its 8 words: computes all 4 gates
// and the c/h update locally (no reduction). Weights streamed from L1/L2
// (reused 8x via word batching), x/h staged in LDS.
// ---------------------------------------------------------------------------
__global__ __launch_bounds__(256)
void char_lstm_kernel(const int* __restrict__ chars, const int* __restrict__ lengths,
                      const float* __restrict__ emb, const float* __restrict__ Wih,
                      const float* __restrict__ Whh, const float* __restrict__ bih,
                      const float* __restrict__ bhh, float* __restrict__ cf)
{
  __shared__ float xs[16][CDIM];
  __shared__ float hsm[16][CHID];
  __shared__ int cidx[16];
  __shared__ int lens[16];
  const int tid = threadIdx.x;
  const int grp = tid >> 7;      // 0..1 (word group)
  const int j = tid & 127;       // hidden index
  const int wb = blockIdx.x * 16;

  for (int i = tid; i < 16 * CHID; i += 256) (&hsm[0][0])[i] = 0.f;
  if (tid < 16) lens[tid] = lengths[wb + tid];
  float c[8];
#pragma unroll
  for (int w = 0; w < 8; ++w) c[w] = 0.f;
  const float bi = bih[j] + bhh[j];
  const float bf = bih[CHID + j] + bhh[CHID + j];
  const float bg = bih[2 * CHID + j] + bhh[2 * CHID + j];
  const float bo = bih[3 * CHID + j] + bhh[3 * CHID + j];

  for (int t = 0; t < CLEN; ++t) {
    __syncthreads();
    if (tid < 16) cidx[tid] = chars[(wb + tid) * CLEN + t];
    __syncthreads();
    {
      int e = tid * 4;
      int wi = e >> 6;
      int k = e & 63;
      const float4 v = *(const float4*)(emb + (size_t)cidx[wi] * CDIM + k);
      *(float4*)(&xs[wi][k]) = v;
    }
    __syncthreads();
    float ai[8], af[8], ag[8], ao[8];
#pragma unroll
    for (int w = 0; w < 8; ++w) { ai[w] = bi; af[w] = bf; ag[w] = bg; ao[w] = bo; }
    // x part (K = 64)
    for (int k = 0; k < CDIM; k += 4) {
      float4 w0 = *(const float4*)(Wih + (size_t)j * CDIM + k);
      float4 w1 = *(const float4*)(Wih + (size_t)(CHID + j) * CDIM + k);
      float4 w2 = *(const float4*)(Wih + (size_t)(2 * CHID + j) * CDIM + k);
      float4 w3 = *(const float4*)(Wih + (size_t)(3 * CHID + j) * CDIM + k);
#pragma unroll
      for (int s = 0; s < 4; ++s) {
        float wiv = (&w0.x)[s], wfv = (&w1.x)[s], wgv = (&w2.x)[s], wov = (&w3.x)[s];
#pragma unroll
        for (int w = 0; w < 8; ++w) {
          float xv = xs[grp * 8 + w][k + s];   // wave-uniform -> LDS broadcast
          ai[w] = fmaf(wiv, xv, ai[w]);
          af[w] = fmaf(wfv, xv, af[w]);
          ag[w] = fmaf(wgv, xv, ag[w]);
          ao[w] = fmaf(wov, xv, ao[w]);
        }
      }
    }
    // h part (K = 128)
    for (int k = 0; k < CHID; k += 4) {
      float4 w0 = *(const float4*)(Whh + (size_t)j * CHID + k);
      float4 w1 = *(const float4*)(Whh + (size_t)(CHID + j) * CHID + k);
      float4 w2 = *(const float4*)(Whh + (size_t)(2 * CHID + j) * CHID + k);
      float4 w3 = *(const float4*)(Whh + (size_t)(3 * CHID + j) * CHID + k);
#pragma unroll
      for (int s = 0; s < 4; ++s) {
        float wiv = (&w0.x)[s], wfv = (&w1.x)[s], wgv = (&w2.x)[s], wov = (&w3.x)[s];
#pragma unroll
        for (int w = 0; w < 8; ++w) {
          float hv = hsm[grp * 8 + w][k + s];
          ai[w] = fmaf(wiv, hv, ai[w]);
          af[w] = fmaf(wfv, hv, af[w]);
          ag[w] = fmaf(wgv, hv, ag[w]);
          ao[w] = fmaf(wov, hv, ao[w]);
        }
      }
    }
    __syncthreads();
#pragma unroll
    for (int w = 0; w < 8; ++w) {
      if (t < lens[grp * 8 + w]) {
        float iv = sigmoidf_(ai[w]);
        float fv = sigmoidf_(af[w]);
        float gv = tanhf_(ag[w]);
        float ov = sigmoidf_(ao[w]);
        c[w] = fv * c[w] + iv * gv;
        hsm[grp * 8 + w][j] = ov * tanhf_(c[w]);
      }
    }
  }
#pragma unroll
  for (int w = 0; w < 8; ++w)
    cf[(size_t)(wb + grp * 8 + w) * CHID + j] = c[w];   // feature = final CELL state
}

// ---------------------------------------------------------------------------
// K2: G_x[t][g] = [word_emb[x[t]] | char_feat[t]] @ w_Wih^T + (bih+bhh)
// Tiled f32 GEMM 64x64x32 with on-the-fly A gather.
// ---------------------------------------------------------------------------
#define BM 64
#define BN 64
#define BK 32
__global__ __launch_bounds__(256)
void gx_gemm_kernel(const int* __restrict__ x, const float* __restrict__ word_emb,
                    const float* __restrict__ char_feat, const float* __restrict__ Wih,
                    const float* __restrict__ bih, const float* __restrict__ bhh,
                    float* __restrict__ Gx)
{
  __shared__ float As[BK][BM + 1];
  __shared__ float Bs[BK][BN + 1];
  __shared__ int xidx[BM];
  const int tid = threadIdx.x;
  const int tx = tid & 15, ty = tid >> 4;
  const int m0 = blockIdx.y * BM;
  const int n0 = blockIdx.x * BN;
  if (tid < BM) xidx[tid] = x[m0 + tid];
  float acc[4][4] = {};
  for (int k0 = 0; k0 < KDIM; k0 += BK) {
    __syncthreads();
    {
      int i = tid >> 5;
      int kk = tid & 31;
#pragma unroll
      for (int l = 0; l < 8; ++l) {
        int row = i + l * 8;
        int k = k0 + kk;
        int tt = m0 + row;
        float v = (k < WDIM) ? word_emb[(size_t)xidx[row] * WDIM + k]
                             : char_feat[(size_t)tt * CHID + (k - WDIM)];
        As[kk][row] = v;
      }
    }
    {
      int jjj = tid >> 5;
      int kk = tid & 31;
#pragma unroll
      for (int l = 0; l < 8; ++l) {
        int col = jjj + l * 8;
        Bs[kk][col] = Wih[(size_t)(n0 + col) * KDIM + k0 + kk];
      }
    }
    __syncthreads();
#pragma unroll
    for (int kk = 0; kk < BK; ++kk) {
      float a[4], b[4];
#pragma unroll
      for (int m = 0; m < 4; ++m) a[m] = As[kk][ty * 4 + m];
#pragma unroll
      for (int n = 0; n < 4; ++n) b[n] = Bs[kk][tx * 4 + n];
#pragma unroll
      for (int m = 0; m < 4; ++m)
#pragma unroll
        for (int n = 0; n < 4; ++n)
          acc[m][n] = fmaf(a[m], b[n], acc[m][n]);
    }
  }
#pragma unroll
  for (int n = 0; n < 4; ++n) {
    int g = n0 + tx * 4 + n;
    float bias = bih[g] + bhh[g];
#pragma unroll
    for (int m = 0; m < 4; ++m) {
      int tt = m0 + ty * 4 + m;
      Gx[(size_t)tt * GDIM + g] = acc[m][n] + bias;
    }
  }
}

// ---------------------------------------------------------------------------
// K3: sequential word LSTM. 32 persistent WGs x 256 threads. WG w owns
// h[w*16 .. w*16+15] -> 64 gate rows; its weight slice LDS-resident TRANSPOSED
// (WlT[k][row], lane-consecutive ds_reads = conflict-free). One flag release +
// spin per step; h double-buffered agent-scope in ws; Gx row prefetched before
// the spin so HBM latency hides under the wait.
// ---------------------------------------------------------------------------
__global__ __launch_bounds__(256, 1)
void word_lstm_seq(const float* __restrict__ Whh, const float* __restrict__ Gx,
                   float* __restrict__ hs, float* h_buf, int* flags)
{
  extern __shared__ float WlT[];   // [512][64] = 128 KiB
  __shared__ float h_lds[WHID];
  __shared__ float red[256];
  const int tid = threadIdx.x;
  const int wg = blockIdx.x;
  const int cchunk = tid >> 6;     // 0..3 k-chunk
  const int lane = tid & 63;

  // stage weight slice transposed: WlT[k][r], r = local gate row
  for (int r = 0; r < 64; ++r) {
    int grow = (r >> 4) * WHID + wg * 16 + (r & 15);
    const float* src = Whh + (size_t)grow * WHID;
    for (int k = tid; k < WHID; k += 256)
      WlT[(size_t)k * 64 + r] = src[k];
  }
  float c_state = 0.f;                                        // lanes < 16 use
  const int grow_f = (tid >> 4) * WHID + wg * 16 + (tid & 15); // tid < 64
  __syncthreads();

  for (int t = 0; t < S_LEN; ++t) {
    float gxv = 0.f;
    if (tid < 64)
      gxv = Gx[(size_t)t * GDIM + grow_f];   // prefetch: completes during spin
    if (t > 0 && tid < 64) {
      while (true) {
        int f = __hip_atomic_load(&flags[tid & (NWG - 1)],
                                  __ATOMIC_ACQUIRE, __HIP_MEMORY_SCOPE_AGENT);
        if (__all(f >= t)) break;
      }
    }
    __syncthreads();
    {
      const float* src = h_buf + ((t + 1) & 1) * WHID;   // h_{t-1}
      for (int k = tid; k < WHID; k += 256)
        h_lds[k] = __hip_atomic_load(src + k, __ATOMIC_RELAXED,
                                     __HIP_MEMORY_SCOPE_AGENT);
    }
    __syncthreads();
    {
      float acc = 0.f;
      const int kb = cchunk * 128;
#pragma unroll 8
      for (int k4 = 0; k4 < 32; ++k4) {
        float4 hv = *(const float4*)(&h_lds[kb + k4 * 4]);
        acc = fmaf(WlT[(size_t)(kb + k4 * 4 + 0) * 64 + lane], hv.x, acc);
        acc = fmaf(WlT[(size_t)(kb + k4 * 4 + 1) * 64 + lane], hv.y, acc);
        acc = fmaf(WlT[(size_t)(kb + k4 * 4 + 2) * 64 + lane], hv.z, acc);
        acc = fmaf(WlT[(size_t)(kb + k4 * 4 + 3) * 64 + lane], hv.w, acc);
      }
      red[tid] = acc;   // red[cchunk*64 + lane]
    }
    __syncthreads();
    if (tid < 64) {
      float s = red[tid] + red[64 + tid] + red[128 + tid] + red[192 + tid] + gxv;
      int jj = tid & 15;
      float si = __shfl(s, jj);
      float sf = __shfl(s, 16 + jj);
      float sg = __shfl(s, 32 + jj);
      float so = __shfl(s, 48 + jj);
      if (tid < 16) {
        float iv = sigmoidf_(si);
        float fv = sigmoidf_(sf);
        float gv = tanhf_(sg);
        float ov = sigmoidf_(so);
        c_state = fv * c_state + iv * gv;
        float hv = ov * tanhf_(c_state);
        const int hidx = wg * 16 + tid;
        hs[(size_t)t * WHID + hidx] = hv;
        __hip_atomic_store(&h_buf[(t & 1) * WHID + hidx], hv,
                           __ATOMIC_RELAXED, __HIP_MEMORY_SCOPE_AGENT);
      }
      __threadfence();   // wave-wide: h stores drained before flag release
      if (tid == 0)
        __hip_atomic_store(&flags[wg], t + 1,
                           __ATOMIC_RELEASE, __HIP_MEMORY_SCOPE_AGENT);
    }
  }
}

// ---------------------------------------------------------------------------
// K4: logits + log_softmax. One 64-lane wave per row t; lane = tag.
// ---------------------------------------------------------------------------
__global__ __launch_bounds__(256)
void tag_kernel(const float* __restrict__ hs, const float* __restrict__ W,
                const float* __restrict__ b, float* __restrict__ out)
{
  const int wave = threadIdx.x >> 6;
  const int lane = threadIdx.x & 63;
  const int t = blockIdx.x * 4 + wave;
  const float* hr = hs + (size_t)t * WHID;
  const float* wr = W + (size_t)lane * WHID;
  float acc = b[lane];
  for (int k = 0; k < WHID; k += 4) {
    float4 wv = *(const float4*)(wr + k);
    float4 hv = *(const float4*)(hr + k);
    acc = fmaf(wv.x, hv.x, acc);
    acc = fmaf(wv.y, hv.y, acc);
    acc = fmaf(wv.z, hv.z, acc);
    acc = fmaf(wv.w, hv.w, acc);
  }
  float m = acc;
#pragma unroll
  for (int off = 32; off > 0; off >>= 1) m = fmaxf(m, __shfl_xor(m, off));
  float e = __expf(acc - m);
  float sum = e;
#pragma unroll
  for (int off = 32; off > 0; off >>= 1) sum += __shfl_xor(sum, off);
  out[(size_t)t * NTAG + lane] = (acc - m) - __logf(sum);
}

extern "C" void kernel_launch(void* const* d_in, const int* in_sizes, int n_in,
                              void* d_out, int out_size, void* d_ws, size_t ws_size,
                              hipStream_t stream)
{
  const int* x          = (const int*)d_in[0];
  const int* chars      = (const int*)d_in[1];
  const int* lengths    = (const int*)d_in[2];
  const float* word_emb = (const float*)d_in[3];
  const float* char_emb = (const float*)d_in[4];
  const float* c_Wih    = (const float*)d_in[5];
  const float* c_Whh    = (const float*)d_in[6];
  const float* c_bih    = (const float*)d_in[7];
  const float* c_bhh    = (const float*)d_in[8];
  const float* w_Wih    = (const float*)d_in[9];
  const float* w_Whh    = (const float*)d_in[10];
  const float* w_bih    = (const float*)d_in[11];
  const float* w_bhh    = (const float*)d_in[12];
  const float* lin_W    = (const float*)d_in[13];
  const float* lin_b    = (const float*)d_in[14];
  float* out = (float*)d_out;

  char* ws = (char*)d_ws;
  // layout: [0,4096) h_buf (2x512 f32) | [4096,4224) flags | pad to 8192 |
  //         char_feat 4 MiB | Gx 64 MiB | hs 16 MiB      (total ~88 MiB)
  float* h_buf     = (float*)ws;
  int*   flags     = (int*)(ws + 4096);
  float* char_feat = (float*)(ws + 8192);
  float* Gx        = (float*)(ws + 8192 + (size_t)S_LEN * CHID * 4);
  float* hs        = (float*)(ws + 8192 + (size_t)S_LEN * CHID * 4
                                        + (size_t)S_LEN * GDIM * 4);

  // zero h0 and flags every call (d_ws is not re-poisoned between replays)
  hipMemsetAsync(ws, 0, 8192, stream);

  char_lstm_kernel<<<S_LEN / 16, 256, 0, stream>>>(
      chars, lengths, char_emb, c_Wih, c_Whh, c_bih, c_bhh, char_feat);

  dim3 g2(GDIM / BN, S_LEN / BM);
  gx_gemm_kernel<<<g2, 256, 0, stream>>>(
      x, word_emb, char_feat, w_Wih, w_bih, w_bhh, Gx);

  hipFuncSetAttribute((const void*)word_lstm_seq,
                      hipFuncAttributeMaxDynamicSharedMemorySize, 64 * WHID * 4);
  word_lstm_seq<<<NWG, 256, 64 * WHID * 4, stream>>>(w_Whh, Gx, hs, h_buf, flags);

  tag_kernel<<<S_LEN / 4, 256, 0, stream>>>(hs, lin_W, lin_b, out);
}

// Round 2
// 28581.924 us; speedup vs baseline: 1.5955x; 1.5955x over previous
//
#include <hip/hip_runtime.h>
#include <hip/hip_bf16.h>

#define S_LEN 8192
#define CLEN 16
#define WDIM 256
#define CDIM 64
#define CHID 128
#define WHID 512
#define GDIM 2048   // 4*WHID
#define NTAG 64
#define KDIM 384    // WDIM + CHID
#define NWG 32      // workgroups in sequential kernel

typedef unsigned long long u64;

__device__ __forceinline__ float sigmoidf_(float x) {
  return 1.0f / (1.0f + __expf(-x));
}
__device__ __forceinline__ float tanhf_(float x) {
  // safe tanh: 1 - 2/(e^{2x}+1); correct limits at +-inf without NaN
  return 1.0f - 2.0f / (__expf(2.0f * x) + 1.0f);
}

// ---------------------------------------------------------------------------
// K1: batched char LSTM. 16 words per block (two groups of 8), 256 threads.
// thread j (0..127) owns hidden unit j for its 8 words: computes all 4 gates
// and the c/h update locally (no reduction). Weights streamed from L1/L2
// (reused 8x via word batching), x/h staged in LDS.
// ---------------------------------------------------------------------------
__global__ __launch_bounds__(256)
void char_lstm_kernel(const int* __restrict__ chars, const int* __restrict__ lengths,
                      const float* __restrict__ emb, const float* __restrict__ Wih,
                      const float* __restrict__ Whh, const float* __restrict__ bih,
                      const float* __restrict__ bhh, float* __restrict__ cf)
{
  __shared__ float xs[16][CDIM];
  __shared__ float hsm[16][CHID];
  __shared__ int cidx[16];
  __shared__ int lens[16];
  const int tid = threadIdx.x;
  const int grp = tid >> 7;      // 0..1 (word group)
  const int j = tid & 127;       // hidden index
  const int wb = blockIdx.x * 16;

  for (int i = tid; i < 16 * CHID; i += 256) (&hsm[0][0])[i] = 0.f;
  if (tid < 16) lens[tid] = lengths[wb + tid];
  float c[8];
#pragma unroll
  for (int w = 0; w < 8; ++w) c[w] = 0.f;
  const float bi = bih[j] + bhh[j];
  const float bf = bih[CHID + j] + bhh[CHID + j];
  const float bg = bih[2 * CHID + j] + bhh[2 * CHID + j];
  const float bo = bih[3 * CHID + j] + bhh[3 * CHID + j];

  for (int t = 0; t < CLEN; ++t) {
    __syncthreads();
    if (tid < 16) cidx[tid] = chars[(wb + tid) * CLEN + t];
    __syncthreads();
    {
      int e = tid * 4;
      int wi = e >> 6;
      int k = e & 63;
      const float4 v = *(const float4*)(emb + (size_t)cidx[wi] * CDIM + k);
      *(float4*)(&xs[wi][k]) = v;
    }
    __syncthreads();
    float ai[8], af[8], ag[8], ao[8];
#pragma unroll
    for (int w = 0; w < 8; ++w) { ai[w] = bi; af[w] = bf; ag[w] = bg; ao[w] = bo; }
    // x part (K = 64)
    for (int k = 0; k < CDIM; k += 4) {
      float4 w0 = *(const float4*)(Wih + (size_t)j * CDIM + k);
      float4 w1 = *(const float4*)(Wih + (size_t)(CHID + j) * CDIM + k);
      float4 w2 = *(const float4*)(Wih + (size_t)(2 * CHID + j) * CDIM + k);
      float4 w3 = *(const float4*)(Wih + (size_t)(3 * CHID + j) * CDIM + k);
#pragma unroll
      for (int s = 0; s < 4; ++s) {
        float wiv = (&w0.x)[s], wfv = (&w1.x)[s], wgv = (&w2.x)[s], wov = (&w3.x)[s];
#pragma unroll
        for (int w = 0; w < 8; ++w) {
          float xv = xs[grp * 8 + w][k + s];   // wave-uniform -> LDS broadcast
          ai[w] = fmaf(wiv, xv, ai[w]);
          af[w] = fmaf(wfv, xv, af[w]);
          ag[w] = fmaf(wgv, xv, ag[w]);
          ao[w] = fmaf(wov, xv, ao[w]);
        }
      }
    }
    // h part (K = 128)
    for (int k = 0; k < CHID; k += 4) {
      float4 w0 = *(const float4*)(Whh + (size_t)j * CHID + k);
      float4 w1 = *(const float4*)(Whh + (size_t)(CHID + j) * CHID + k);
      float4 w2 = *(const float4*)(Whh + (size_t)(2 * CHID + j) * CHID + k);
      float4 w3 = *(const float4*)(Whh + (size_t)(3 * CHID + j) * CHID + k);
#pragma unroll
      for (int s = 0; s < 4; ++s) {
        float wiv = (&w0.x)[s], wfv = (&w1.x)[s], wgv = (&w2.x)[s], wov = (&w3.x)[s];
#pragma unroll
        for (int w = 0; w < 8; ++w) {
          float hv = hsm[grp * 8 + w][k + s];
          ai[w] = fmaf(wiv, hv, ai[w]);
          af[w] = fmaf(wfv, hv, af[w]);
          ag[w] = fmaf(wgv, hv, ag[w]);
          ao[w] = fmaf(wov, hv, ao[w]);
        }
      }
    }
    __syncthreads();
#pragma unroll
    for (int w = 0; w < 8; ++w) {
      if (t < lens[grp * 8 + w]) {
        float iv = sigmoidf_(ai[w]);
        float fv = sigmoidf_(af[w]);
        float gv = tanhf_(ag[w]);
        float ov = sigmoidf_(ao[w]);
        c[w] = fv * c[w] + iv * gv;
        hsm[grp * 8 + w][j] = ov * tanhf_(c[w]);
      }
    }
  }
#pragma unroll
  for (int w = 0; w < 8; ++w)
    cf[(size_t)(wb + grp * 8 + w) * CHID + j] = c[w];   // feature = final CELL state
}

// ---------------------------------------------------------------------------
// K2: G_x[t][g] = [word_emb[x[t]] | char_feat[t]] @ w_Wih^T + (bih+bhh)
// Tiled f32 GEMM 64x64x32 with on-the-fly A gather.
// ---------------------------------------------------------------------------
#define BM 64
#define BN 64
#define BK 32
__global__ __launch_bounds__(256)
void gx_gemm_kernel(const int* __restrict__ x, const float* __restrict__ word_emb,
                    const float* __restrict__ char_feat, const float* __restrict__ Wih,
                    const float* __restrict__ bih, const float* __restrict__ bhh,
                    float* __restrict__ Gx)
{
  __shared__ float As[BK][BM + 1];
  __shared__ float Bs[BK][BN + 1];
  __shared__ int xidx[BM];
  const int tid = threadIdx.x;
  const int tx = tid & 15, ty = tid >> 4;
  const int m0 = blockIdx.y * BM;
  const int n0 = blockIdx.x * BN;
  if (tid < BM) xidx[tid] = x[m0 + tid];
  float acc[4][4] = {};
  for (int k0 = 0; k0 < KDIM; k0 += BK) {
    __syncthreads();
    {
      int i = tid >> 5;
      int kk = tid & 31;
#pragma unroll
      for (int l = 0; l < 8; ++l) {
        int row = i + l * 8;
        int k = k0 + kk;
        int tt = m0 + row;
        float v = (k < WDIM) ? word_emb[(size_t)xidx[row] * WDIM + k]
                             : char_feat[(size_t)tt * CHID + (k - WDIM)];
        As[kk][row] = v;
      }
    }
    {
      int jjj = tid >> 5;
      int kk = tid & 31;
#pragma unroll
      for (int l = 0; l < 8; ++l) {
        int col = jjj + l * 8;
        Bs[kk][col] = Wih[(size_t)(n0 + col) * KDIM + k0 + kk];
      }
    }
    __syncthreads();
#pragma unroll
    for (int kk = 0; kk < BK; ++kk) {
      float a[4], b[4];
#pragma unroll
      for (int m = 0; m < 4; ++m) a[m] = As[kk][ty * 4 + m];
#pragma unroll
      for (int n = 0; n < 4; ++n) b[n] = Bs[kk][tx * 4 + n];
#pragma unroll
      for (int m = 0; m < 4; ++m)
#pragma unroll
        for (int n = 0; n < 4; ++n)
          acc[m][n] = fmaf(a[m], b[n], acc[m][n]);
    }
  }
#pragma unroll
  for (int n = 0; n < 4; ++n) {
    int g = n0 + tx * 4 + n;
    float bias = bih[g] + bhh[g];
#pragma unroll
    for (int m = 0; m < 4; ++m) {
      int tt = m0 + ty * 4 + m;
      Gx[(size_t)tt * GDIM + g] = acc[m][n] + bias;
    }
  }
}

// ---------------------------------------------------------------------------
// K3: sequential word LSTM, tagged-slot sync.
// 32 persistent WGs x 256 threads. WG w owns h[w*16..w*16+15] -> 64 gate rows;
// weight slice LDS-resident transposed (WlT[k][row], lane-consecutive = no
// bank conflicts). Sync: each h element is a u64 slot {hi32 = epoch tag,
// lo32 = f32 bits}, written with ONE relaxed agent-scope 8B atomic store at
// end of step t (tag = t+1) into buf[(t+1)&1]. Consumers poll their 2 slots
// directly -- data and flag arrive together, so NO fence, NO separate h load,
// NO release/acquire. Own slice is kept in LDS (no self round trip).
// Double-buffer safety: a producer overwrites buf[p] at step t+2 only after
// reading every WG's tag-(t+1) slice, which transitively requires every WG to
// have consumed tag-t from buf[p].
// ---------------------------------------------------------------------------
__global__ __launch_bounds__(256, 1)
void word_lstm_seq(const float* __restrict__ Whh, const float* __restrict__ Gx,
                   float* __restrict__ hs, u64* hbuf)
{
  extern __shared__ float WlT[];   // [512][64] = 128 KiB
  __shared__ float h_lds[WHID];
  __shared__ float red[256];
  const int tid = threadIdx.x;
  const int wg = blockIdx.x;
  const int cchunk = tid >> 6;     // 0..3 k-chunk
  const int lane = tid & 63;

  // stage weight slice transposed: WlT[k][r], r = local gate row
  for (int r = 0; r < 64; ++r) {
    int grow = (r >> 4) * WHID + wg * 16 + (r & 15);
    const float* src = Whh + (size_t)grow * WHID;
    for (int k = tid; k < WHID; k += 256)
      WlT[(size_t)k * 64 + r] = src[k];
  }
  for (int k = tid; k < WHID; k += 256) h_lds[k] = 0.f;   // h_{-1} = 0
  float c_state = 0.f;                                        // lanes < 16 use
  const int grow_f = (tid >> 4) * WHID + wg * 16 + (tid & 15); // tid < 64
  const bool is_own = ((tid >> 3) == wg);  // this thread's 2 slots are own-WG
  __syncthreads();

  for (int t = 0; t < S_LEN; ++t) {
    float gxv = 0.f;
    if (tid < 64)
      gxv = Gx[(size_t)t * GDIM + grow_f];   // prefetch: completes during poll
    if (t > 0 && !is_own) {
      const u64* base = hbuf + (size_t)(t & 1) * WHID;
      const int k0 = 2 * tid;
      u64 a, b;
      const unsigned want = (unsigned)t;
      while (true) {
        a = __hip_atomic_load(base + k0, __ATOMIC_RELAXED,
                              __HIP_MEMORY_SCOPE_AGENT);
        b = __hip_atomic_load(base + k0 + 1, __ATOMIC_RELAXED,
                              __HIP_MEMORY_SCOPE_AGENT);
        if ((unsigned)(a >> 32) == want && (unsigned)(b >> 32) == want) break;
      }
      h_lds[k0]     = __uint_as_float((unsigned)a);
      h_lds[k0 + 1] = __uint_as_float((unsigned)b);
    }
    __syncthreads();   // h_lds complete (pollers + own-slice from finalize)
    {
      float acc = 0.f;
      const int kb = cchunk * 128;
#pragma unroll 8
      for (int k4 = 0; k4 < 32; ++k4) {
        float4 hv = *(const float4*)(&h_lds[kb + k4 * 4]);
        acc = fmaf(WlT[(size_t)(kb + k4 * 4 + 0) * 64 + lane], hv.x, acc);
        acc = fmaf(WlT[(size_t)(kb + k4 * 4 + 1) * 64 + lane], hv.y, acc);
        acc = fmaf(WlT[(size_t)(kb + k4 * 4 + 2) * 64 + lane], hv.z, acc);
        acc = fmaf(WlT[(size_t)(kb + k4 * 4 + 3) * 64 + lane], hv.w, acc);
      }
      red[tid] = acc;   // red[cchunk*64 + lane]
    }
    __syncthreads();
    if (tid < 64) {
      float s = red[tid] + red[64 + tid] + red[128 + tid] + red[192 + tid] + gxv;
      int jj = tid & 15;
      float si = __shfl(s, jj);
      float sf = __shfl(s, 16 + jj);
      float sg = __shfl(s, 32 + jj);
      float so = __shfl(s, 48 + jj);
      if (tid < 16) {
        float iv = sigmoidf_(si);
        float fv = sigmoidf_(sf);
        float gv = tanhf_(sg);
        float ov = sigmoidf_(so);
        c_state = fv * c_state + iv * gv;
        float hv = ov * tanhf_(c_state);
        const int hidx = wg * 16 + tid;
        // publish FIRST: single 8B atomic carries {tag = t+1, value}
        u64 pkt = ((u64)(unsigned)(t + 1) << 32) | (u64)__float_as_uint(hv);
        __hip_atomic_store(&hbuf[(size_t)((t + 1) & 1) * WHID + hidx], pkt,
                           __ATOMIC_RELAXED, __HIP_MEMORY_SCOPE_AGENT);
        hs[(size_t)t * WHID + hidx] = hv;
        h_lds[hidx] = hv;          // own slice for next step (skip self poll)
      }
    }
  }
}

// ---------------------------------------------------------------------------
// K4: logits + log_softmax. One 64-lane wave per row t; lane = tag.
// ---------------------------------------------------------------------------
__global__ __launch_bounds__(256)
void tag_kernel(const float* __restrict__ hs, const float* __restrict__ W,
                const float* __restrict__ b, float* __restrict__ out)
{
  const int wave = threadIdx.x >> 6;
  const int lane = threadIdx.x & 63;
  const int t = blockIdx.x * 4 + wave;
  const float* hr = hs + (size_t)t * WHID;
  const float* wr = W + (size_t)lane * WHID;
  float acc = b[lane];
  for (int k = 0; k < WHID; k += 4) {
    float4 wv = *(const float4*)(wr + k);
    float4 hv = *(const float4*)(hr + k);
    acc = fmaf(wv.x, hv.x, acc);
    acc = fmaf(wv.y, hv.y, acc);
    acc = fmaf(wv.z, hv.z, acc);
    acc = fmaf(wv.w, hv.w, acc);
  }
  float m = acc;
#pragma unroll
  for (int off = 32; off > 0; off >>= 1) m = fmaxf(m, __shfl_xor(m, off));
  float e = __expf(acc - m);
  float sum = e;
#pragma unroll
  for (int off = 32; off > 0; off >>= 1) sum += __shfl_xor(sum, off);
  out[(size_t)t * NTAG + lane] = (acc - m) - __logf(sum);
}

extern "C" void kernel_launch(void* const* d_in, const int* in_sizes, int n_in,
                              void* d_out, int out_size, void* d_ws, size_t ws_size,
                              hipStream_t stream)
{
  const int* x          = (const int*)d_in[0];
  const int* chars      = (const int*)d_in[1];
  const int* lengths    = (const int*)d_in[2];
  const float* word_emb = (const float*)d_in[3];
  const float* char_emb = (const float*)d_in[4];
  const float* c_Wih    = (const float*)d_in[5];
  const float* c_Whh    = (const float*)d_in[6];
  const float* c_bih    = (const float*)d_in[7];
  const float* c_bhh    = (const float*)d_in[8];
  const float* w_Wih    = (const float*)d_in[9];
  const float* w_Whh    = (const float*)d_in[10];
  const float* w_bih    = (const float*)d_in[11];
  const float* w_bhh    = (const float*)d_in[12];
  const float* lin_W    = (const float*)d_in[13];
  const float* lin_b    = (const float*)d_in[14];
  float* out = (float*)d_out;

  char* ws = (char*)d_ws;
  // layout: [0,8192) hbuf (2 x 512 u64 tagged slots) |
  //         char_feat 4 MiB | Gx 64 MiB | hs 16 MiB   (total ~84 MiB)
  u64*   hbuf      = (u64*)ws;
  float* char_feat = (float*)(ws + 8192);
  float* Gx        = (float*)(ws + 8192 + (size_t)S_LEN * CHID * 4);
  float* hs        = (float*)(ws + 8192 + (size_t)S_LEN * CHID * 4
                                        + (size_t)S_LEN * GDIM * 4);

  // zero tags every call (tag 0 never matches an expected epoch t >= 1)
  hipMemsetAsync(ws, 0, 8192, stream);

  char_lstm_kernel<<<S_LEN / 16, 256, 0, stream>>>(
      chars, lengths, char_emb, c_Wih, c_Whh, c_bih, c_bhh, char_feat);

  dim3 g2(GDIM / BN, S_LEN / BM);
  gx_gemm_kernel<<<g2, 256, 0, stream>>>(
      x, word_emb, char_feat, w_Wih, w_bih, w_bhh, Gx);

  hipFuncSetAttribute((const void*)word_lstm_seq,
                      hipFuncAttributeMaxDynamicSharedMemorySize, 64 * WHID * 4);
  word_lstm_seq<<<NWG, 256, 64 * WHID * 4, stream>>>(w_Whh, Gx, hs, hbuf);

  tag_kernel<<<S_LEN / 4, 256, 0, stream>>>(hs, lin_W, lin_b, out);
}

// Round 3
// 15855.916 us; speedup vs baseline: 2.8761x; 1.8026x over previous
//
#include <hip/hip_runtime.h>
#include <hip/hip_bf16.h>

#define S_LEN 8192
#define CLEN 16
#define WDIM 256
#define CDIM 64
#define CHID 128
#define WHID 512
#define GDIM 2048   // 4*WHID
#define NTAG 64
#define KDIM 384    // WDIM + CHID
#define NWG 32      // workgroups in sequential kernel

typedef unsigned long long u64;

__device__ __forceinline__ float sigmoidf_(float x) {
  return 1.0f / (1.0f + __expf(-x));
}
__device__ __forceinline__ float tanhf_(float x) {
  // safe tanh: 1 - 2/(e^{2x}+1); correct limits at +-inf without NaN
  return 1.0f - 2.0f / (__expf(2.0f * x) + 1.0f);
}

// ---------------------------------------------------------------------------
// K1: batched char LSTM. 16 words per block (two groups of 8), 256 threads.
// thread j (0..127) owns hidden unit j for its 8 words: computes all 4 gates
// and the c/h update locally (no reduction). Weights streamed from L1/L2
// (reused 8x via word batching), x/h staged in LDS.
// ---------------------------------------------------------------------------
__global__ __launch_bounds__(256)
void char_lstm_kernel(const int* __restrict__ chars, const int* __restrict__ lengths,
                      const float* __restrict__ emb, const float* __restrict__ Wih,
                      const float* __restrict__ Whh, const float* __restrict__ bih,
                      const float* __restrict__ bhh, float* __restrict__ cf)
{
  __shared__ float xs[16][CDIM];
  __shared__ float hsm[16][CHID];
  __shared__ int cidx[16];
  __shared__ int lens[16];
  const int tid = threadIdx.x;
  const int grp = tid >> 7;      // 0..1 (word group)
  const int j = tid & 127;       // hidden index
  const int wb = blockIdx.x * 16;

  for (int i = tid; i < 16 * CHID; i += 256) (&hsm[0][0])[i] = 0.f;
  if (tid < 16) lens[tid] = lengths[wb + tid];
  float c[8];
#pragma unroll
  for (int w = 0; w < 8; ++w) c[w] = 0.f;
  const float bi = bih[j] + bhh[j];
  const float bf = bih[CHID + j] + bhh[CHID + j];
  const float bg = bih[2 * CHID + j] + bhh[2 * CHID + j];
  const float bo = bih[3 * CHID + j] + bhh[3 * CHID + j];

  for (int t = 0; t < CLEN; ++t) {
    __syncthreads();
    if (tid < 16) cidx[tid] = chars[(wb + tid) * CLEN + t];
    __syncthreads();
    {
      int e = tid * 4;
      int wi = e >> 6;
      int k = e & 63;
      const float4 v = *(const float4*)(emb + (size_t)cidx[wi] * CDIM + k);
      *(float4*)(&xs[wi][k]) = v;
    }
    __syncthreads();
    float ai[8], af[8], ag[8], ao[8];
#pragma unroll
    for (int w = 0; w < 8; ++w) { ai[w] = bi; af[w] = bf; ag[w] = bg; ao[w] = bo; }
    // x part (K = 64)
    for (int k = 0; k < CDIM; k += 4) {
      float4 w0 = *(const float4*)(Wih + (size_t)j * CDIM + k);
      float4 w1 = *(const float4*)(Wih + (size_t)(CHID + j) * CDIM + k);
      float4 w2 = *(const float4*)(Wih + (size_t)(2 * CHID + j) * CDIM + k);
      float4 w3 = *(const float4*)(Wih + (size_t)(3 * CHID + j) * CDIM + k);
#pragma unroll
      for (int s = 0; s < 4; ++s) {
        float wiv = (&w0.x)[s], wfv = (&w1.x)[s], wgv = (&w2.x)[s], wov = (&w3.x)[s];
#pragma unroll
        for (int w = 0; w < 8; ++w) {
          float xv = xs[grp * 8 + w][k + s];   // wave-uniform -> LDS broadcast
          ai[w] = fmaf(wiv, xv, ai[w]);
          af[w] = fmaf(wfv, xv, af[w]);
          ag[w] = fmaf(wgv, xv, ag[w]);
          ao[w] = fmaf(wov, xv, ao[w]);
        }
      }
    }
    // h part (K = 128)
    for (int k = 0; k < CHID; k += 4) {
      float4 w0 = *(const float4*)(Whh + (size_t)j * CHID + k);
      float4 w1 = *(const float4*)(Whh + (size_t)(CHID + j) * CHID + k);
      float4 w2 = *(const float4*)(Whh + (size_t)(2 * CHID + j) * CHID + k);
      float4 w3 = *(const float4*)(Whh + (size_t)(3 * CHID + j) * CHID + k);
#pragma unroll
      for (int s = 0; s < 4; ++s) {
        float wiv = (&w0.x)[s], wfv = (&w1.x)[s], wgv = (&w2.x)[s], wov = (&w3.x)[s];
#pragma unroll
        for (int w = 0; w < 8; ++w) {
          float hv = hsm[grp * 8 + w][k + s];
          ai[w] = fmaf(wiv, hv, ai[w]);
          af[w] = fmaf(wfv, hv, af[w]);
          ag[w] = fmaf(wgv, hv, ag[w]);
          ao[w] = fmaf(wov, hv, ao[w]);
        }
      }
    }
    __syncthreads();
#pragma unroll
    for (int w = 0; w < 8; ++w) {
      if (t < lens[grp * 8 + w]) {
        float iv = sigmoidf_(ai[w]);
        float fv = sigmoidf_(af[w]);
        float gv = tanhf_(ag[w]);
        float ov = sigmoidf_(ao[w]);
        c[w] = fv * c[w] + iv * gv;
        hsm[grp * 8 + w][j] = ov * tanhf_(c[w]);
      }
    }
  }
#pragma unroll
  for (int w = 0; w < 8; ++w)
    cf[(size_t)(wb + grp * 8 + w) * CHID + j] = c[w];   // feature = final CELL state
}

// ---------------------------------------------------------------------------
// K2: G_x[t][g] = [word_emb[x[t]] | char_feat[t]] @ w_Wih^T + (bih+bhh)
// Tiled f32 GEMM 64x64x32 with on-the-fly A gather.
// ---------------------------------------------------------------------------
#define BM 64
#define BN 64
#define BK 32
__global__ __launch_bounds__(256)
void gx_gemm_kernel(const int* __restrict__ x, const float* __restrict__ word_emb,
                    const float* __restrict__ char_feat, const float* __restrict__ Wih,
                    const float* __restrict__ bih, const float* __restrict__ bhh,
                    float* __restrict__ Gx)
{
  __shared__ float As[BK][BM + 1];
  __shared__ float Bs[BK][BN + 1];
  __shared__ int xidx[BM];
  const int tid = threadIdx.x;
  const int tx = tid & 15, ty = tid >> 4;
  const int m0 = blockIdx.y * BM;
  const int n0 = blockIdx.x * BN;
  if (tid < BM) xidx[tid] = x[m0 + tid];
  float acc[4][4] = {};
  for (int k0 = 0; k0 < KDIM; k0 += BK) {
    __syncthreads();
    {
      int i = tid >> 5;
      int kk = tid & 31;
#pragma unroll
      for (int l = 0; l < 8; ++l) {
        int row = i + l * 8;
        int k = k0 + kk;
        int tt = m0 + row;
        float v = (k < WDIM) ? word_emb[(size_t)xidx[row] * WDIM + k]
                             : char_feat[(size_t)tt * CHID + (k - WDIM)];
        As[kk][row] = v;
      }
    }
    {
      int jjj = tid >> 5;
      int kk = tid & 31;
#pragma unroll
      for (int l = 0; l < 8; ++l) {
        int col = jjj + l * 8;
        Bs[kk][col] = Wih[(size_t)(n0 + col) * KDIM + k0 + kk];
      }
    }
    __syncthreads();
#pragma unroll
    for (int kk = 0; kk < BK; ++kk) {
      float a[4], b[4];
#pragma unroll
      for (int m = 0; m < 4; ++m) a[m] = As[kk][ty * 4 + m];
#pragma unroll
      for (int n = 0; n < 4; ++n) b[n] = Bs[kk][tx * 4 + n];
#pragma unroll
      for (int m = 0; m < 4; ++m)
#pragma unroll
        for (int n = 0; n < 4; ++n)
          acc[m][n] = fmaf(a[m], b[n], acc[m][n]);
    }
  }
#pragma unroll
  for (int n = 0; n < 4; ++n) {
    int g = n0 + tx * 4 + n;
    float bias = bih[g] + bhh[g];
#pragma unroll
    for (int m = 0; m < 4; ++m) {
      int tt = m0 + ty * 4 + m;
      Gx[(size_t)tt * GDIM + g] = acc[m][n] + bias;
    }
  }
}

// ---------------------------------------------------------------------------
// K3: sequential word LSTM, v3: register-resident weights + per-wave polling.
// 32 persistent WGs x 256 threads (4 waves). WG w owns h[w*16..w*16+15] ->
// 64 gate rows. Lane l (0..63) of wave c owns gate row (l>>4)*512+w*16+(l&15),
// k-chunk [128c..128c+128): 128 weight f32 in VGPRs (static indexing).
// Per step: wave c polls ONLY its 128 h-values (tagged u64 slots, relaxed
// agent loads; data+tag arrive together), shares them via its private h_lds
// chunk (wave-synchronous, threadfence_block), runs a pure-VALU matvec
// (weights from VGPRs, h via uniform-address LDS broadcast), stages partial
// into red[t&1][] -- ONE barrier -- wave0 finalizes (64-lane transcendentals,
// 16-lane c/h update) and publishes via atomic_exchange (RMW executes at the
// coherence point -> prompt visibility). Waves 1-3 poll step t+1 while wave0
// finalizes step t (pipelined).
// Double-buffer safety: WG w overwrites buf[p] slot (tag t+2) only after all
// its waves detected every tag-(t+1) slot, which transitively requires every
// WG's waves to have consumed tag-t from buf[p].
// ---------------------------------------------------------------------------
__global__ __launch_bounds__(256, 1)
void word_lstm_seq(const float* __restrict__ Whh, const float* __restrict__ Gx,
                   float* __restrict__ hs, u64* hbuf)
{
  __shared__ float h_lds[WHID];
  __shared__ float red[2][256];
  const int tid = threadIdx.x;
  const int wg = blockIdx.x;
  const int cc = tid >> 6;       // k-chunk 0..3
  const int lane = tid & 63;
  const int kb = cc * 128;

  // per-lane weight chunk -> VGPRs (one-time, off critical path)
  const int grow = (lane >> 4) * WHID + wg * 16 + (lane & 15);
  float wl[128];
  {
    const float* wsrc = Whh + (size_t)grow * WHID + kb;
#pragma unroll
    for (int k = 0; k < 128; ++k) wl[k] = wsrc[k];
  }

  float c_state = 0.f;   // used by lanes<16 of wave 0

  for (int t = 0; t < S_LEN; ++t) {
    float gxv = 0.f;
    if (tid < 64)
      gxv = Gx[(size_t)t * GDIM + grow];   // wave0 only; issued before poll
    // poll this wave's 128 h_{t-1} values (2 tagged slots per lane)
    if (t > 0) {
      const u64* base = hbuf + (size_t)(t & 1) * WHID + kb;
      const int s0 = 2 * lane;
      u64 a, b;
      const unsigned want = (unsigned)t;
      while (true) {
        a = __hip_atomic_load(base + s0, __ATOMIC_RELAXED,
                              __HIP_MEMORY_SCOPE_AGENT);
        b = __hip_atomic_load(base + s0 + 1, __ATOMIC_RELAXED,
                              __HIP_MEMORY_SCOPE_AGENT);
        if ((unsigned)(a >> 32) == want && (unsigned)(b >> 32) == want) break;
      }
      float2 hv2 = make_float2(__uint_as_float((unsigned)a),
                               __uint_as_float((unsigned)b));
      *(float2*)(&h_lds[kb + s0]) = hv2;
    } else {
      *(float2*)(&h_lds[kb + 2 * lane]) = make_float2(0.f, 0.f);
    }
    __threadfence_block();   // wave-synchronous LDS: writes visible to own wave
    // pure-VALU matvec: weights in VGPRs, h broadcast from LDS
    float acc = 0.f;
#pragma unroll
    for (int g = 0; g < 32; ++g) {
      float4 hv = *(const float4*)(&h_lds[kb + 4 * g]);
      acc = fmaf(wl[4 * g + 0], hv.x, acc);
      acc = fmaf(wl[4 * g + 1], hv.y, acc);
      acc = fmaf(wl[4 * g + 2], hv.z, acc);
      acc = fmaf(wl[4 * g + 3], hv.w, acc);
    }
    red[t & 1][tid] = acc;
    __syncthreads();   // the ONLY barrier per step
    if (tid < 64) {
      const float* rp = &red[t & 1][0];
      float s = rp[tid] + rp[64 + tid] + rp[128 + tid] + rp[192 + tid] + gxv;
      // 64-lane parallel nonlinearity (gate 2 = tanh, others sigmoid)
      float act = ((tid >> 4) == 2) ? tanhf_(s) : sigmoidf_(s);
      int jj = tid & 15;
      float iv = __shfl(act, jj);
      float fv = __shfl(act, 16 + jj);
      float gv = __shfl(act, 32 + jj);
      float ov = __shfl(act, 48 + jj);
      if (tid < 16) {
        c_state = fv * c_state + iv * gv;
        float hv = ov * tanhf_(c_state);
        const int hidx = wg * 16 + tid;
        u64 pkt = ((u64)(unsigned)(t + 1) << 32) | (u64)__float_as_uint(hv);
        // publish FIRST; RMW executes at coherence point (prompt visibility)
        (void)__hip_atomic_exchange(
            &hbuf[(size_t)((t + 1) & 1) * WHID + hidx], pkt,
            __ATOMIC_RELAXED, __HIP_MEMORY_SCOPE_AGENT);
        hs[(size_t)t * WHID + hidx] = hv;
      }
    }
  }
}

// ---------------------------------------------------------------------------
// K4: logits + log_softmax. One 64-lane wave per row t; lane = tag.
// ---------------------------------------------------------------------------
__global__ __launch_bounds__(256)
void tag_kernel(const float* __restrict__ hs, const float* __restrict__ W,
                const float* __restrict__ b, float* __restrict__ out)
{
  const int wave = threadIdx.x >> 6;
  const int lane = threadIdx.x & 63;
  const int t = blockIdx.x * 4 + wave;
  const float* hr = hs + (size_t)t * WHID;
  const float* wr = W + (size_t)lane * WHID;
  float acc = b[lane];
  for (int k = 0; k < WHID; k += 4) {
    float4 wv = *(const float4*)(wr + k);
    float4 hv = *(const float4*)(hr + k);
    acc = fmaf(wv.x, hv.x, acc);
    acc = fmaf(wv.y, hv.y, acc);
    acc = fmaf(wv.z, hv.z, acc);
    acc = fmaf(wv.w, hv.w, acc);
  }
  float m = acc;
#pragma unroll
  for (int off = 32; off > 0; off >>= 1) m = fmaxf(m, __shfl_xor(m, off));
  float e = __expf(acc - m);
  float sum = e;
#pragma unroll
  for (int off = 32; off > 0; off >>= 1) sum += __shfl_xor(sum, off);
  out[(size_t)t * NTAG + lane] = (acc - m) - __logf(sum);
}

extern "C" void kernel_launch(void* const* d_in, const int* in_sizes, int n_in,
                              void* d_out, int out_size, void* d_ws, size_t ws_size,
                              hipStream_t stream)
{
  const int* x          = (const int*)d_in[0];
  const int* chars      = (const int*)d_in[1];
  const int* lengths    = (const int*)d_in[2];
  const float* word_emb = (const float*)d_in[3];
  const float* char_emb = (const float*)d_in[4];
  const float* c_Wih    = (const float*)d_in[5];
  const float* c_Whh    = (const float*)d_in[6];
  const float* c_bih    = (const float*)d_in[7];
  const float* c_bhh    = (const float*)d_in[8];
  const float* w_Wih    = (const float*)d_in[9];
  const float* w_Whh    = (const float*)d_in[10];
  const float* w_bih    = (const float*)d_in[11];
  const float* w_bhh    = (const float*)d_in[12];
  const float* lin_W    = (const float*)d_in[13];
  const float* lin_b    = (const float*)d_in[14];
  float* out = (float*)d_out;

  char* ws = (char*)d_ws;
  // layout: [0,8192) hbuf (2 x 512 u64 tagged slots) |
  //         char_feat 4 MiB | Gx 64 MiB | hs 16 MiB   (total ~84 MiB)
  u64*   hbuf      = (u64*)ws;
  float* char_feat = (float*)(ws + 8192);
  float* Gx        = (float*)(ws + 8192 + (size_t)S_LEN * CHID * 4);
  float* hs        = (float*)(ws + 8192 + (size_t)S_LEN * CHID * 4
                                        + (size_t)S_LEN * GDIM * 4);

  // zero tags every call (tag 0 never matches an expected epoch t >= 1)
  hipMemsetAsync(ws, 0, 8192, stream);

  char_lstm_kernel<<<S_LEN / 16, 256, 0, stream>>>(
      chars, lengths, char_emb, c_Wih, c_Whh, c_bih, c_bhh, char_feat);

  dim3 g2(GDIM / BN, S_LEN / BM);
  gx_gemm_kernel<<<g2, 256, 0, stream>>>(
      x, word_emb, char_feat, w_Wih, w_bih, w_bhh, Gx);

  word_lstm_seq<<<NWG, 256, 0, stream>>>(w_Whh, Gx, hs, hbuf);

  tag_kernel<<<S_LEN / 4, 256, 0, stream>>>(hs, lin_W, lin_b, out);
}